// Round 12
// baseline (5579.556 us; speedup 1.0000x reference)
//
#include <hip/hip_runtime.h>
#include <stdint.h>

#define NB 512
#define NH 512
#define NG 2048
#define NF 32
#define NSQ 64
#define NO 32

typedef unsigned short ushort_t;
typedef __attribute__((ext_vector_type(8))) short bf16x8;
typedef __attribute__((ext_vector_type(4))) unsigned int uiv4;
typedef __attribute__((ext_vector_type(16))) float f32x16;

__device__ __forceinline__ float sigf(float x){ return 1.f/(1.f+__expf(-x)); }
__device__ __forceinline__ float tanh_(float x){ return 1.f-2.f/(1.f+__expf(2.f*x)); }
__device__ __forceinline__ unsigned short f2bf(float f){
  uint32_t u=__float_as_uint(f); u=(u+0x7FFFu+((u>>16)&1u))>>16; return (unsigned short)u; }
__device__ __forceinline__ float bf2f(unsigned short u){ return __uint_as_float(((uint32_t)u)<<16); }
__device__ __forceinline__ float bf2f_s(short s){ return __uint_as_float(((uint32_t)(unsigned short)s)<<16); }

__device__ __forceinline__ bf16x8 vload16(const ushort_t* p){
  union { uiv4 u; bf16x8 b; } c; c.u = *(const uiv4*)p; return c.b;
}

// ---------------- zero: c (1MB) + hA (1MB) ----------------
__global__ __launch_bounds__(256)
void zero_k(float4* __restrict__ p, int n) {
  int i = blockIdx.x * 256 + threadIdx.x;
  if (i < n) p[i] = make_float4(0.f, 0.f, 0.f, 0.f);
}

// ---------------- prep: pack Wh (plain) and Wh+Wd@Wx (folded) into MFMA frag order ----
// Layout: [cb(32)][qh(2)][kh(2)][s(16)][part(2)][lane(64)][e(8)] bf16 (R3-proven).
// k = kh*256+s*16+(lane>>5)*8+e ; q = cb*64+qh*32+(lane&31); col=(q&3)*NH+(q>>2).
__global__ __launch_bounds__(256)
void prep_w_k(const float* __restrict__ Wh, const float* __restrict__ Wd,
              const float* __restrict__ Wx,
              ushort_t* __restrict__ Wpk, ushort_t* __restrict__ Wppk)
{
  __shared__ float Whs[16][33];
  __shared__ float Folds[16][33];
  __shared__ float Wds[16][32];
  __shared__ float Wxs[32][33];
  const int p = blockIdx.x;
  const int s = p & 15, kh = (p >> 4) & 1, qh = (p >> 5) & 1, cb = p >> 6;
  const int k0 = kh * 256 + s * 16;
  const int tid = threadIdx.x;

  for (int it = 0; it < 2; ++it) {
    int i = it * 256 + tid; int kl = i >> 5, o = i & 31;
    Wds[kl][o] = Wd[(size_t)(k0 + kl) * NO + o];
  }
  for (int it = 0; it < 4; ++it) {
    int i = it * 256 + tid; int o = i >> 5, ql = i & 31;
    int q = cb * 64 + qh * 32 + ql;
    int col = (q & 3) * NH + (q >> 2);
    Wxs[o][ql] = Wx[(size_t)o * NG + col];
  }
  for (int it = 0; it < 2; ++it) {
    int i = it * 256 + tid; int kl = i >> 5, ql = i & 31;
    int q = cb * 64 + qh * 32 + ql;
    int col = (q & 3) * NH + (q >> 2);
    Whs[kl][ql] = Wh[(size_t)(k0 + kl) * NG + col];
  }
  __syncthreads();
  for (int it = 0; it < 2; ++it) {
    int i = it * 256 + tid; int kl = i >> 5, ql = i & 31;
    float f = 0.f;
    #pragma unroll
    for (int o = 0; o < 32; ++o) f += Wds[kl][o] * Wxs[o][ql];
    Folds[kl][ql] = Whs[kl][ql] + f;
  }
  __syncthreads();
  const size_t base = (size_t)p * 1024;
  for (int it = 0; it < 4; ++it) {
    int i = it * 256 + tid;             // part*512 + l*8 + e
    int part = i >> 9, l = (i >> 3) & 63, e = i & 7;
    int kl = (l >> 5) * 8 + e;
    int ql = l & 31;
    float v = Whs[kl][ql], vf = Folds[kl][ql];
    unsigned short o1, o2;
    if (part == 0) { o1 = f2bf(v); o2 = f2bf(vf); }
    else {
      o1 = f2bf(v - bf2f(f2bf(v)));
      o2 = f2bf(vf - bf2f(f2bf(vf)));
    }
    Wpk[base + i] = o1;
    Wppk[base + i] = o2;
  }
}

// ---------------- prep: pack Wx into frag order [cb][qh][kh][part][lane][e] ----------------
__global__ __launch_bounds__(256)
void prep_wx_k(const float* __restrict__ Wx, ushort_t* __restrict__ Wxpk) {
  size_t i0 = ((size_t)blockIdx.x * 256 + threadIdx.x) * 4;   // 131072 total, grid 128
  int e0 = (int)(i0 & 7);
  int l = (int)((i0 >> 3) & 63);
  int part = (int)((i0 >> 9) & 1);
  int kh = (int)((i0 >> 10) & 1);
  int qh = (int)((i0 >> 11) & 1);
  int cb = (int)(i0 >> 12);
  int q = cb * 64 + qh * 32 + (l & 31);
  int col = (q & 3) * NH + (q >> 2);
  unsigned short r[4];
  #pragma unroll
  for (int d = 0; d < 4; ++d) {
    int f = kh * 16 + (l >> 5) * 8 + e0 + d;
    float v = Wx[(size_t)f * NG + col];
    unsigned short h = f2bf(v);
    r[d] = part ? f2bf(v - bf2f(h)) : h;
  }
  *(ushort4*)&Wxpk[i0] = make_ushort4(r[0], r[1], r[2], r[3]);
}

// ---------------- prep: pack x into frag order [t][rb(16)][kh(2)][part][lane][e] ----------------
// total 2^21 elements -> grid 2048 x 256 thr x 4 elem (R3-proven, exact coverage)
__global__ __launch_bounds__(256)
void prep_x_k(const float* __restrict__ x, ushort_t* __restrict__ xpk) {
  size_t i0 = ((size_t)blockIdx.x * 256 + threadIdx.x) * 4;
  int e0 = (int)(i0 & 7);
  int l = (int)((i0 >> 3) & 63);
  int part = (int)((i0 >> 9) & 1);
  int kh = (int)((i0 >> 10) & 1);
  int rb = (int)((i0 >> 11) & 15);
  int t = (int)(i0 >> 15);
  int row = rb * 32 + (l & 31);
  int f = kh * 16 + (l >> 5) * 8 + e0;
  float4 v = *(const float4*)&x[(size_t)row * (NSQ * NF) + t * NF + f];
  float vv[4] = { v.x, v.y, v.z, v.w };
  unsigned short r[4];
  #pragma unroll
  for (int d = 0; d < 4; ++d) {
    unsigned short h = f2bf(vv[d]);
    r[d] = part ? f2bf(vv[d] - bf2f(h)) : h;
  }
  *(ushort4*)&xpk[i0] = make_ushort4(r[0], r[1], r[2], r[3]);
}

// ---------------- prep: permuted biases (plain + folded) ----------------
__global__ __launch_bounds__(256)
void prep_bias_k(const float* __restrict__ b, const float* __restrict__ bd,
                 const float* __restrict__ Wx, float* __restrict__ b_p,
                 float* __restrict__ bp_p) {
  int q = blockIdx.x * 256 + threadIdx.x;
  int g = (q & 3) * NH + (q >> 2);
  float v = b[g];
  float f = v;
  #pragma unroll
  for (int o = 0; o < 32; ++o) f += bd[o] * Wx[(size_t)o * NG + g];
  b_p[q] = v; bp_p[q] = f;
}

// ---------------- fused LSTM step: 64x64 tile, 8 K-eighth waves ----------------
// Grid 256 = 8 RB (64 rows) x 32 cb (64 packed q). blockIdx = RB*32+cb so the 8
// blocks sharing weight panel cb land on one XCD (cb%8) -> panel L2-resident.
// 512 thr = 8 waves, wave kq owns K in [kq*64, kq*64+64): zero duplicate fetch
// (64 MB/step device-wide, vs R3's 96 MB). Each wave: 2 row-groups x 2 q-groups,
// 12 MFMAs per k16 chunk (Ah*Bh + Ah*Bl + Al*Bh split-precision). K-split merged
// via LDS atomics (persist-proven). Dispatch boundary = coherence (R3-proven).
template<bool WARM, bool EMIT_PRED>
__global__ __launch_bounds__(512, 2)
void lstm_step_k(const ushort_t* __restrict__ hin, float* __restrict__ c_st,
                 ushort_t* __restrict__ hout,
                 const ushort_t* __restrict__ Wpk, const float* __restrict__ bias_p,
                 const ushort_t* __restrict__ xpk, const ushort_t* __restrict__ Wxpk,
                 const float* __restrict__ Wd, const float* __restrict__ bd,
                 float* __restrict__ out, int s_out, int t)
{
  __shared__ float Zs[64][68];
  __shared__ float red[8][64];
  __shared__ float wdcol[512];
  __shared__ float bias_s[64];

  const int tid = threadIdx.x;
  const int lane = tid & 63;
  const int kq = tid >> 6;              // K-eighth 0..7
  const int RB = (int)blockIdx.x >> 5;  // row-block (64 rows)
  const int cb = (int)blockIdx.x & 31;  // col-block (64 packed q)
  const int kh = kq >> 2;
  const int sb = (kq & 3) * 4;

  if (EMIT_PRED) wdcol[tid] = Wd[(size_t)tid * NO + cb];
  if (tid < 64) bias_s[tid] = bias_p[cb * 64 + tid];
  __syncthreads();

  const ushort_t* A0 = hin + ((size_t)((RB * 4 + kh) * 16 + sb)) * 1024 + lane * 8;
  const ushort_t* A1 = hin + ((size_t)((RB * 4 + 2 + kh) * 16 + sb)) * 1024 + lane * 8;
  const ushort_t* B0 = Wpk + ((size_t)((cb * 4 + kh) * 16 + sb)) * 1024 + lane * 8;
  const ushort_t* B1 = Wpk + ((size_t)((cb * 4 + 2 + kh) * 16 + sb)) * 1024 + lane * 8;

  f32x16 acc00, acc01, acc10, acc11;
  #pragma unroll
  for (int i = 0; i < 16; ++i) { acc00[i]=0.f; acc01[i]=0.f; acc10[i]=0.f; acc11[i]=0.f; }

  float pacc0 = 0.f, pacc1 = 0.f;

  bf16x8 fa0h[2], fa0l[2], fa1h[2], fa1l[2], fb0h[2], fb0l[2], fb1h[2], fb1l[2];
  fa0h[0]=vload16(A0);     fa0l[0]=vload16(A0+512);
  fa1h[0]=vload16(A1);     fa1l[0]=vload16(A1+512);
  fb0h[0]=vload16(B0);     fb0l[0]=vload16(B0+512);
  fb1h[0]=vload16(B1);     fb1l[0]=vload16(B1+512);

  #pragma unroll
  for (int i = 0; i < 4; ++i) {
    const int cur = i & 1, nxt = cur ^ 1;
    if (i < 3) {
      const int o = (i + 1) * 1024;
      fa0h[nxt]=vload16(A0+o); fa0l[nxt]=vload16(A0+o+512);
      fa1h[nxt]=vload16(A1+o); fa1l[nxt]=vload16(A1+o+512);
      fb0h[nxt]=vload16(B0+o); fb0l[nxt]=vload16(B0+o+512);
      fb1h[nxt]=vload16(B1+o); fb1l[nxt]=vload16(B1+o+512);
    }
    const bf16x8 a0h=fa0h[cur], a0l=fa0l[cur], a1h=fa1h[cur], a1l=fa1l[cur];
    const bf16x8 b0h=fb0h[cur], b0l=fb0l[cur], b1h=fb1h[cur], b1l=fb1l[cur];
    acc00 = __builtin_amdgcn_mfma_f32_32x32x16_bf16(a0h, b0h, acc00, 0,0,0);
    acc01 = __builtin_amdgcn_mfma_f32_32x32x16_bf16(a0h, b1h, acc01, 0,0,0);
    acc10 = __builtin_amdgcn_mfma_f32_32x32x16_bf16(a1h, b0h, acc10, 0,0,0);
    acc11 = __builtin_amdgcn_mfma_f32_32x32x16_bf16(a1h, b1h, acc11, 0,0,0);
    acc00 = __builtin_amdgcn_mfma_f32_32x32x16_bf16(a0h, b0l, acc00, 0,0,0);
    acc01 = __builtin_amdgcn_mfma_f32_32x32x16_bf16(a0h, b1l, acc01, 0,0,0);
    acc10 = __builtin_amdgcn_mfma_f32_32x32x16_bf16(a1h, b0l, acc10, 0,0,0);
    acc11 = __builtin_amdgcn_mfma_f32_32x32x16_bf16(a1h, b1l, acc11, 0,0,0);
    acc00 = __builtin_amdgcn_mfma_f32_32x32x16_bf16(a0l, b0h, acc00, 0,0,0);
    acc01 = __builtin_amdgcn_mfma_f32_32x32x16_bf16(a0l, b1h, acc01, 0,0,0);
    acc10 = __builtin_amdgcn_mfma_f32_32x32x16_bf16(a1l, b0h, acc10, 0,0,0);
    acc11 = __builtin_amdgcn_mfma_f32_32x32x16_bf16(a1l, b1h, acc11, 0,0,0);
    if (EMIT_PRED) {
      const int kw = kq * 64 + i * 16 + (lane >> 5) * 8;
      float4 w0 = *(const float4*)&wdcol[kw];
      float4 w1 = *(const float4*)&wdcol[kw + 4];
      pacc0 += (bf2f_s(a0h[0])+bf2f_s(a0l[0]))*w0.x + (bf2f_s(a0h[1])+bf2f_s(a0l[1]))*w0.y
             + (bf2f_s(a0h[2])+bf2f_s(a0l[2]))*w0.z + (bf2f_s(a0h[3])+bf2f_s(a0l[3]))*w0.w
             + (bf2f_s(a0h[4])+bf2f_s(a0l[4]))*w1.x + (bf2f_s(a0h[5])+bf2f_s(a0l[5]))*w1.y
             + (bf2f_s(a0h[6])+bf2f_s(a0l[6]))*w1.z + (bf2f_s(a0h[7])+bf2f_s(a0l[7]))*w1.w;
      pacc1 += (bf2f_s(a1h[0])+bf2f_s(a1l[0]))*w0.x + (bf2f_s(a1h[1])+bf2f_s(a1l[1]))*w0.y
             + (bf2f_s(a1h[2])+bf2f_s(a1l[2]))*w0.z + (bf2f_s(a1h[3])+bf2f_s(a1l[3]))*w0.w
             + (bf2f_s(a1h[4])+bf2f_s(a1l[4]))*w1.x + (bf2f_s(a1h[5])+bf2f_s(a1l[5]))*w1.y
             + (bf2f_s(a1h[6])+bf2f_s(a1l[6]))*w1.z + (bf2f_s(a1h[7])+bf2f_s(a1l[7]))*w1.w;
    }
  }

  // ---- x contribution (warmup): waves kq=0,1 handle xs=kq (K=16 each) ----
  if (WARM && kq < 2) {
    const ushort_t* X0 = xpk + ((size_t)((t * 16 + RB * 2 + 0) * 2 + kq)) * 1024 + lane * 8;
    const ushort_t* X1 = xpk + ((size_t)((t * 16 + RB * 2 + 1) * 2 + kq)) * 1024 + lane * 8;
    const ushort_t* W0 = Wxpk + ((size_t)((cb * 2 + 0) * 2 + kq)) * 1024 + lane * 8;
    const ushort_t* W1 = Wxpk + ((size_t)((cb * 2 + 1) * 2 + kq)) * 1024 + lane * 8;
    bf16x8 ax0h = vload16(X0), ax0l = vload16(X0 + 512);
    bf16x8 ax1h = vload16(X1), ax1l = vload16(X1 + 512);
    bf16x8 wx0h = vload16(W0), wx0l = vload16(W0 + 512);
    bf16x8 wx1h = vload16(W1), wx1l = vload16(W1 + 512);
    acc00 = __builtin_amdgcn_mfma_f32_32x32x16_bf16(ax0h, wx0h, acc00, 0,0,0);
    acc01 = __builtin_amdgcn_mfma_f32_32x32x16_bf16(ax0h, wx1h, acc01, 0,0,0);
    acc10 = __builtin_amdgcn_mfma_f32_32x32x16_bf16(ax1h, wx0h, acc10, 0,0,0);
    acc11 = __builtin_amdgcn_mfma_f32_32x32x16_bf16(ax1h, wx1h, acc11, 0,0,0);
    acc00 = __builtin_amdgcn_mfma_f32_32x32x16_bf16(ax0h, wx0l, acc00, 0,0,0);
    acc01 = __builtin_amdgcn_mfma_f32_32x32x16_bf16(ax0h, wx1l, acc01, 0,0,0);
    acc10 = __builtin_amdgcn_mfma_f32_32x32x16_bf16(ax1h, wx0l, acc10, 0,0,0);
    acc11 = __builtin_amdgcn_mfma_f32_32x32x16_bf16(ax1h, wx1l, acc11, 0,0,0);
    acc00 = __builtin_amdgcn_mfma_f32_32x32x16_bf16(ax0l, wx0h, acc00, 0,0,0);
    acc01 = __builtin_amdgcn_mfma_f32_32x32x16_bf16(ax0l, wx1h, acc01, 0,0,0);
    acc10 = __builtin_amdgcn_mfma_f32_32x32x16_bf16(ax1l, wx0h, acc10, 0,0,0);
    acc11 = __builtin_amdgcn_mfma_f32_32x32x16_bf16(ax1l, wx1h, acc11, 0,0,0);
  }

  if (EMIT_PRED) {
    pacc0 += __shfl_xor(pacc0, 32);
    pacc1 += __shfl_xor(pacc1, 32);
    if (lane < 32) { red[kq][lane] = pacc0; red[kq][32 + lane] = pacc1; }
  }

  // ---- K-split merge through LDS (wave kq=0 stores, others atomicAdd) ----
  const int qb = lane & 31;
  const int rbase = 4 * (lane >> 5);
  if (kq == 0) {
    #pragma unroll
    for (int r = 0; r < 16; ++r) {
      int rm = (r & 3) + 8 * (r >> 2) + rbase;
      Zs[rm][qb] = acc00[r];
      Zs[rm][32 + qb] = acc01[r];
      Zs[32 + rm][qb] = acc10[r];
      Zs[32 + rm][32 + qb] = acc11[r];
    }
  }
  __syncthreads();
  if (kq != 0) {
    #pragma unroll
    for (int r = 0; r < 16; ++r) {
      int rm = (r & 3) + 8 * (r >> 2) + rbase;
      atomicAdd(&Zs[rm][qb], acc00[r]);
      atomicAdd(&Zs[rm][32 + qb], acc01[r]);
      atomicAdd(&Zs[32 + rm][qb], acc10[r]);
      atomicAdd(&Zs[32 + rm][32 + qb], acc11[r]);
    }
  }
  __syncthreads();

  // ---- gates + c/h update: thread -> (row 0..63, 2 j's) ----
  {
    const int row = tid >> 3, jq = tid & 7;
    float4 z0 = *(const float4*)&Zs[row][jq * 8];
    float4 z1 = *(const float4*)&Zs[row][jq * 8 + 4];
    float4 bvA = *(const float4*)&bias_s[jq * 8];
    float4 bvB = *(const float4*)&bias_s[jq * 8 + 4];
    float zi0 = z0.x + bvA.x, zf0 = z0.y + bvA.y, zg0 = z0.z + bvA.z, zo0 = z0.w + bvA.w;
    float zi1 = z1.x + bvB.x, zf1 = z1.y + bvB.y, zg1 = z1.z + bvB.z, zo1 = z1.w + bvB.w;
    const size_t cidx = (size_t)(RB * 64 + row) * NH + cb * 16 + jq * 2;
    float2 cold = *(const float2*)&c_st[cidx];
    float c0 = sigf(zf0) * cold.x + sigf(zi0) * tanh_(zg0);
    float c1 = sigf(zf1) * cold.y + sigf(zi1) * tanh_(zg1);
    *(float2*)&c_st[cidx] = make_float2(c0, c1);
    float h0 = sigf(zo0) * tanh_(c0);
    float h1 = sigf(zo1) * tanh_(c1);
    unsigned short hh0 = f2bf(h0), hh1 = f2bf(h1);
    unsigned short hl0 = f2bf(h0 - bf2f(hh0)), hl1 = f2bf(h1 - bf2f(hh1));
    const int rg = row >> 5;
    const int lane_w = (jq >> 2) * 32 + (row & 31);
    const int e0 = (jq * 2) & 7;
    size_t hb = ((size_t)((RB * 2 + rg) * 2 + (cb >> 4)) * 16 + (cb & 15)) * 1024
              + lane_w * 8 + e0;
    *(ushort2*)&hout[hb]       = make_ushort2(hh0, hh1);
    *(ushort2*)&hout[hb + 512] = make_ushort2(hl0, hl1);
  }

  if (EMIT_PRED && tid < 64) {
    float s = red[0][tid] + red[1][tid] + red[2][tid] + red[3][tid]
            + red[4][tid] + red[5][tid] + red[6][tid] + red[7][tid] + bd[cb];
    out[((size_t)(RB * 64 + tid) * NSQ + s_out) * NO + cb] = s;
  }
}

// ---------------- final pred_63 from packed h (R3-proven) ----------------
__global__ __launch_bounds__(256)
void final_pred_k(const ushort_t* __restrict__ hin, const float* __restrict__ Wd,
                  const float* __restrict__ bd, float* __restrict__ out)
{
  __shared__ float red[8][32];
  __shared__ float wdcol[512];
  const int tid = threadIdx.x;
  const int rb = (int)blockIdx.x >> 5, o = (int)blockIdx.x & 31;
  const int rowBase = rb * 32;
  wdcol[tid] = Wd[(size_t)tid * NO + o];
  wdcol[256 + tid] = Wd[(size_t)(256 + tid) * NO + o];
  __syncthreads();
  const int prow = tid & 31, ks = tid >> 5;
  const int khp = ks >> 2;
  float pacc = 0.f;
  #pragma unroll
  for (int c4 = 0; c4 < 4; ++c4) {
    int sch = (ks & 3) * 4 + c4;
    const ushort_t* base = hin + ((size_t)(rb * 2 + khp) * 16 + sch) * 1024;
    #pragma unroll
    for (int half = 0; half < 2; ++half) {
      bf16x8 hv = vload16(base + (half * 32 + prow) * 8);
      bf16x8 lv = vload16(base + 512 + (half * 32 + prow) * 8);
      int kb = khp * 256 + sch * 16 + half * 8;
      #pragma unroll
      for (int e = 0; e < 8; ++e)
        pacc += (bf2f_s(hv[e]) + bf2f_s(lv[e])) * wdcol[kb + e];
    }
  }
  red[ks][prow] = pacc;
  __syncthreads();
  if (tid < 32) {
    float ssum = red[0][tid] + red[1][tid] + red[2][tid] + red[3][tid]
               + red[4][tid] + red[5][tid] + red[6][tid] + red[7][tid] + bd[o];
    out[((size_t)(rowBase + tid) * NSQ + 63) * NO + o] = ssum;
  }
}

extern "C" void kernel_launch(void* const* d_in, const int* in_sizes, int n_in,
                              void* d_out, int out_size, void* d_ws, size_t ws_size,
                              hipStream_t stream) {
  (void)in_sizes; (void)n_in; (void)out_size; (void)ws_size;
  const float* x  = (const float*)d_in[0];   // (512, 64, 32)
  const float* Wx = (const float*)d_in[1];   // (32, 2048)
  const float* Wh = (const float*)d_in[2];   // (512, 2048)
  const float* b  = (const float*)d_in[3];   // (2048,)
  const float* Wd = (const float*)d_in[4];   // (512, 32)
  const float* bd = (const float*)d_in[5];   // (32,)
  float* out = (float*)d_out;                // (512, 64, 32)

  // ws layout: 16,007,168 B total (== R3's proven footprint)
  char* w = (char*)d_ws;
  float* c       = (float*)w;                              // 1 MB (zeroed)
  ushort_t* hA   = (ushort_t*)(w + 1048576);               // 1 MB (zeroed)
  ushort_t* hB   = (ushort_t*)(w + 2097152);               // 1 MB
  ushort_t* Wpk  = (ushort_t*)(w + 3145728);               // 4 MB
  ushort_t* Wppk = (ushort_t*)(w + 7340032);               // 4 MB
  ushort_t* Wxpk = (ushort_t*)(w + 11534336);              // 256 KB
  ushort_t* xpk  = (ushort_t*)(w + 11796480);              // 4 MB
  float* b_p  = (float*)(w + 15990784);                    // 8 KB
  float* bp_p = (float*)(w + 15998976);                    // 8 KB

  zero_k<<<512, 256, 0, stream>>>((float4*)w, 131072);     // c + hA
  prep_w_k<<<2048, 256, 0, stream>>>(Wh, Wd, Wx, Wpk, Wppk);
  prep_wx_k<<<128, 256, 0, stream>>>(Wx, Wxpk);
  prep_x_k<<<2048, 256, 0, stream>>>(x, xpk);
  prep_bias_k<<<8, 256, 0, stream>>>(b, bd, Wx, b_p, bp_p);

  ushort_t* hb[2] = { hA, hB };
  int p = 0;
  for (int tt = 0; tt < 64; ++tt) {
    lstm_step_k<true, false><<<256, 512, 0, stream>>>(
        hb[p], c, hb[p ^ 1], Wpk, b_p, xpk, Wxpk,
        Wd, bd, nullptr, 0, tt);
    p ^= 1;
  }
  for (int s = 1; s < 64; ++s) {
    lstm_step_k<false, true><<<256, 512, 0, stream>>>(
        hb[p], c, hb[p ^ 1], Wppk, bp_p, nullptr, nullptr,
        Wd, bd, out, s - 1, 0);
    p ^= 1;
  }
  final_pred_k<<<512, 256, 0, stream>>>(hb[p], Wd, bd, out);
}